// Round 1
// baseline (54.152 us; speedup 1.0000x reference)
//
#include <hip/hip_runtime.h>

#define EPS 1e-5f

// ---------------------------------------------------------------------------
// Kernel 1: full unmasked sum of nll = log(tau) + (dt+eps)/tau over all N.
// float4 vectorized grid-stride; wave shuffle reduce; one atomic per block.
// ---------------------------------------------------------------------------
__global__ __launch_bounds__(256) void tau_loss_main(
    const float* __restrict__ tau,
    const float* __restrict__ dt,
    float* __restrict__ out,
    int n, float inv_div) {
    const int n4 = n >> 2;
    int tid = blockIdx.x * blockDim.x + threadIdx.x;
    const int stride = gridDim.x * blockDim.x;

    float acc = 0.0f;
    const float4* t4 = (const float4*)tau;
    const float4* d4 = (const float4*)dt;
    for (int i = tid; i < n4; i += stride) {
        float4 t = t4[i];
        float4 d = d4[i];
        acc += __logf(t.x) + __fdividef(d.x + EPS, t.x);
        acc += __logf(t.y) + __fdividef(d.y + EPS, t.y);
        acc += __logf(t.z) + __fdividef(d.z + EPS, t.z);
        acc += __logf(t.w) + __fdividef(d.w + EPS, t.w);
    }
    // scalar tail (n not divisible by 4) — handled by first few threads
    int tail_base = n4 << 2;
    int tail_i = tail_base + tid;
    if (tail_i < n) {
        float t = tau[tail_i];
        acc += __logf(t) + __fdividef(dt[tail_i] + EPS, t);
    }

    // wave(64) reduce
    #pragma unroll
    for (int off = 32; off > 0; off >>= 1)
        acc += __shfl_down(acc, off, 64);

    __shared__ float smem[4];  // 256 threads = 4 waves
    int wave = threadIdx.x >> 6;
    int lane = threadIdx.x & 63;
    if (lane == 0) smem[wave] = acc;
    __syncthreads();
    if (threadIdx.x == 0) {
        float s = smem[0] + smem[1] + smem[2] + smem[3];
        atomicAdd(out, s * inv_div);
    }
}

// ---------------------------------------------------------------------------
// Kernel 2: subtract boundary (first & last of each segment) contributions.
// One thread per segment; dedupe start==end (length-1 segments) exactly as
// the reference's idempotent mask.set(False). Block-reduced -> 1 atomic/block.
// ---------------------------------------------------------------------------
__global__ __launch_bounds__(256) void tau_loss_boundary(
    const float* __restrict__ tau,
    const float* __restrict__ dt,
    const int* __restrict__ offsets,
    float* __restrict__ out,
    int nseg, float inv_div) {
    int k = blockIdx.x * blockDim.x + threadIdx.x;

    float sub = 0.0f;
    if (k < nseg) {
        int s = offsets[k];
        int e = offsets[k + 1] - 1;
        float ts = tau[s];
        sub = __logf(ts) + __fdividef(dt[s] + EPS, ts);
        if (e != s) {
            float te = tau[e];
            sub += __logf(te) + __fdividef(dt[e] + EPS, te);
        }
    }

    #pragma unroll
    for (int off = 32; off > 0; off >>= 1)
        sub += __shfl_down(sub, off, 64);

    __shared__ float smem[4];
    int wave = threadIdx.x >> 6;
    int lane = threadIdx.x & 63;
    if (lane == 0) smem[wave] = sub;
    __syncthreads();
    if (threadIdx.x == 0) {
        float s = smem[0] + smem[1] + smem[2] + smem[3];
        atomicAdd(out, -s * inv_div);
    }
}

extern "C" void kernel_launch(void* const* d_in, const int* in_sizes, int n_in,
                              void* d_out, int out_size, void* d_ws, size_t ws_size,
                              hipStream_t stream) {
    const float* tau = (const float*)d_in[0];
    const float* dt  = (const float*)d_in[1];
    const int* offsets = (const int*)d_in[2];
    float* out = (float*)d_out;

    const int n = in_sizes[0];
    const int n_off = in_sizes[2];          // B + 1
    const int nseg = n_off - 1;
    const float inv_div = 1.0f / (float)n_off;

    // zero the accumulator (harness poisons d_out; does not re-zero between replays)
    hipMemsetAsync(d_out, 0, sizeof(float), stream);

    // main streaming pass: 2048 blocks x 256 = 8192 waves (fills the chip)
    tau_loss_main<<<2048, 256, 0, stream>>>(tau, dt, out, n, inv_div);

    // boundary subtraction: one thread per segment
    int bblocks = (nseg + 255) / 256;
    if (bblocks > 0)
        tau_loss_boundary<<<bblocks, 256, 0, stream>>>(tau, dt, offsets, out, nseg, inv_div);
}